// Round 7
// baseline (272.924 us; speedup 1.0000x reference)
//
#include <hip/hip_runtime.h>
#include <math.h>

constexpr int B = 2, C = 64, H = 80, W = 80, HW = H * W, COUT = 64;
constexpr int NPIX = B * HW;   // 12800

typedef __attribute__((ext_vector_type(8))) short short8;   // 8 bf16
typedef __attribute__((ext_vector_type(4))) float f32x4;
typedef __attribute__((ext_vector_type(2))) float f32x2;

__device__ inline ushort f2bf(float f) {
  unsigned u = __float_as_uint(f);
  unsigned r = u + 0x7fff + ((u >> 16) & 1);   // RNE
  return (ushort)(r >> 16);
}

__device__ inline f32x2 unpack_bf2(unsigned u) {
  f32x2 r;
  r.x = __uint_as_float(u << 16);
  r.y = __uint_as_float(u & 0xffff0000u);
  return r;
}

// bilinear-combine 2 bf16 channels x 4 corners, repack to 2 bf16 (1 v_perm)
__device__ inline unsigned bilin_pack(unsigned a, unsigned b, unsigned c,
                                      unsigned d, f32x2 c00, f32x2 c01,
                                      f32x2 c10, f32x2 c11) {
  f32x2 p = unpack_bf2(a) * c00;
  p += unpack_bf2(b) * c01;
  p += unpack_bf2(c) * c10;
  p += unpack_bf2(d) * c11;
  unsigned lo = __float_as_uint(p.x) + 0x8000u;
  unsigned hi = __float_as_uint(p.y) + 0x8000u;
  return __builtin_amdgcn_perm(hi, lo, 0x07060302);
}

// global -> LDS DMA, 16B per lane, linear dest (wave-uniform base + lane*16)
__device__ __forceinline__ void gload_lds16(const ushort* g, ushort* s) {
  __builtin_amdgcn_global_load_lds(
      (const __attribute__((address_space(1))) void*)g,
      (__attribute__((address_space(3))) void*)s, 16, 0, 0);
}

// ---------------------------------------------------------------------------
// Weight prep body (grid-stride over this branch's swizzled tables).
// ---------------------------------------------------------------------------
template <int K, int NT>
__device__ void prep_body(int pb, int nblk, const float* __restrict__ w_off,
                          const float* __restrict__ b_off,
                          const float* __restrict__ w_mask,
                          const float* __restrict__ b_mask,
                          const float* __restrict__ w_dcn,
                          ushort* __restrict__ wtbs, float* __restrict__ bcomb,
                          ushort* __restrict__ wdts) {
  constexpr int KK = K * K, C3 = 3 * KK;
  const int n1 = KK * 2 * NT * 512;
  const int n2 = C3;
  const int n3 = KK * 2 * 4 * 512;
  const int total = n1 + n2 + n3;
  for (int i = pb * 256 + threadIdx.x; i < total; i += nblk * 256) {
    if (i < n1) {
      int e = i & 7, l = (i >> 3) & 63;
      int blk512 = i >> 9;
      int nt = blk512 % NT, th = blk512 / NT;
      int half = th & 1, t = th >> 1;
      int n = nt * 16 + (l & 15);
      int ci = half * 32 + (l >> 4) * 8 + e;
      float v = 0.f;
      if (n < 2 * KK) v = w_off[(n * C + ci) * KK + t];
      else if (n < C3) v = w_mask[((n - 2 * KK) * C + ci) * KK + t];
      wtbs[i] = f2bf(v);
    } else if (i < n1 + n2) {
      int co = i - n1;
      bcomb[co] = (co < 2 * KK) ? b_off[co] : b_mask[co - 2 * KK];
    } else {
      int j = i - n1 - n2;
      int e = j & 7, l = (j >> 3) & 63;
      int blk512 = j >> 9;
      int jt = blk512 & 3, th = blk512 >> 2;
      int half = th & 1, t = th >> 1;
      int co = jt * 16 + (l & 15);
      int ci = half * 32 + (l >> 4) * 8 + e;
      wdts[j] = f2bf(w_dcn[(co * C + ci) * KK + t]);
    }
  }
}

// ---------------------------------------------------------------------------
// setup_all: blocks 0..199 transpose NCHW->NHWC bf16 (+zero region for OOB
// staging redirects); rest weight prep.
// ---------------------------------------------------------------------------
__global__ __launch_bounds__(256) void setup_all(
    const float* __restrict__ x, ushort* __restrict__ xhb,
    const float* __restrict__ w_off3, const float* __restrict__ b_off3,
    const float* __restrict__ w_mask3, const float* __restrict__ b_mask3,
    const float* __restrict__ w_dcn3, ushort* __restrict__ wtbs3,
    float* __restrict__ bc3, ushort* __restrict__ wdts3,
    const float* __restrict__ w_off5, const float* __restrict__ b_off5,
    const float* __restrict__ w_mask5, const float* __restrict__ b_mask5,
    const float* __restrict__ w_dcn5, ushort* __restrict__ wtbs5,
    float* __restrict__ bc5, ushort* __restrict__ wdts5,
    const float* __restrict__ w_off7, const float* __restrict__ b_off7,
    const float* __restrict__ w_mask7, const float* __restrict__ b_mask7,
    const float* __restrict__ w_dcn7, ushort* __restrict__ wtbs7,
    float* __restrict__ bc7, ushort* __restrict__ wdts7) {
  __shared__ float tile[64][65];
  int blk = blockIdx.x;
  if (blk < 200) {
    int b = blk / (HW / 64);
    int p0 = (blk % (HW / 64)) * 64;
    int lane = threadIdx.x & 63, row = threadIdx.x >> 6;
    if (blk == 0) {                        // 640-ushort zero region
      for (int i = threadIdx.x; i < 640; i += 256)
        xhb[(size_t)B * HW * C + i] = 0;
    }
#pragma unroll
    for (int it = 0; it < 16; ++it) {
      int ci = it * 4 + row;
      tile[ci][lane] = x[(size_t)(b * C + ci) * HW + p0 + lane];
    }
    __syncthreads();
#pragma unroll
    for (int it = 0; it < 16; ++it) {
      int pl = it * 4 + row;
      xhb[((size_t)b * HW + p0 + pl) * C + lane] = f2bf(tile[lane][pl]);
    }
  } else {
    int pb = blk - 200;
    prep_body<7, 10>(pb, 256, w_off7, b_off7, w_mask7, b_mask7, w_dcn7, wtbs7,
                     bc7, wdts7);
    prep_body<5, 6>(pb, 256, w_off5, b_off5, w_mask5, b_mask5, w_dcn5, wtbs5,
                    bc5, wdts5);
    prep_body<3, 2>(pb, 256, w_off3, b_off3, w_mask3, b_mask3, w_dcn3, wtbs3,
                    bc3, wdts3);
  }
}

// ---------------------------------------------------------------------------
// Phase A helper: conv for one branch, tiles [j0w, j0w+ntw) of this wave,
// A from the shared 7x24 swizzled window (row offset RO for K<7), output
// py/px/mask written to the LDS cv planes [3][KK][17] (pad 17 = conflict-free).
// Values bit-identical to the previous conv_all epilogue.
// ---------------------------------------------------------------------------
template <int K, int NT, int NMAX>
__device__ __forceinline__ void convA(int j0w, int ntw, int y, int x0, int l,
                                      int lm, int lk, const ushort* win,
                                      const ushort* __restrict__ wtbs,
                                      const float* __restrict__ bcomb,
                                      float* cvb) {
  constexpr int PAD = K / 2, KK = K * K, C3 = 3 * KK, RO = (7 - K) / 2;
  f32x4 acc[NMAX];
#pragma unroll
  for (int j = 0; j < NMAX; ++j) acc[j] = f32x4{0.f, 0.f, 0.f, 0.f};
#pragma unroll
  for (int t = 0; t < KK; ++t) {
    int ky = t / K, kx = t % K;
    int c = 4 + lm + kx - PAD;           // window col, in [1,23)
    int h = (4 + c) & 7;                 // == global px&7 (x0 % 16 == 0)
    const ushort* ap = win + ((ky + RO) * 24 + c) * 64;
    short8 A0v = *(const short8*)(ap + ((lk ^ h) * 8));
    short8 A1v = *(const short8*)(ap + (((lk + 4) ^ h) * 8));
    const ushort* fbase = wtbs + (size_t)(t * 2) * NT * 512 + l * 8;
#pragma unroll
    for (int jj = 0; jj < NMAX; ++jj)
      if (jj < ntw)
        acc[jj] = __builtin_amdgcn_mfma_f32_16x16x32_bf16(
            A0v, *(const short8*)(fbase + (size_t)(j0w + jj) * 512), acc[jj],
            0, 0, 0);
#pragma unroll
    for (int jj = 0; jj < NMAX; ++jj)
      if (jj < ntw)
        acc[jj] = __builtin_amdgcn_mfma_f32_16x16x32_bf16(
            A1v, *(const short8*)(fbase + (size_t)(NT + j0w + jj) * 512),
            acc[jj], 0, 0, 0);
  }
  // Epilogue to LDS cv planes. D map: col(n)=lm -> co, row(m)=lk*4+r -> pixel.
#pragma unroll
  for (int jj = 0; jj < NMAX; ++jj) {
    if (jj >= ntw) continue;
    int co = (j0w + jj) * 16 + lm;
    if (co >= C3) continue;              // zero-padded tail tiles
    float bs = bcomb[co];
    bool isoff = co < 2 * KK;
    int tp = isoff ? (co >> 1) : (co - 2 * KK);
    int plane = isoff ? (co & 1) : 2;    // 0=py, 1=px, 2=mask
    float* dst = cvb + plane * KK * 17 + tp * 17 + lk * 4;
#pragma unroll
    for (int r = 0; r < 4; ++r) {
      int xr = x0 + lk * 4 + r;
      float v = acc[jj][r] + bs;
      if (isoff) {
        v += (co & 1) ? (float)(xr - PAD + tp % K)    // px
                      : (float)(y - PAD + tp / K);    // py
      } else {
        v = 1.f / (1.f + expf(-v));
      }
      dst[r] = v;
    }
  }
}

// ---------------------------------------------------------------------------
// Phase B helper: deformable sampling + einsum for one branch, taps
// [base, base+cnt) of this wave (exact split, no dummy taps). Offsets come
// from the LDS cv planes (broadcast ds_read). Gathers/pack identical to v6.
// ---------------------------------------------------------------------------
template <int K>
__device__ __forceinline__ void dcnB(int base, int cnt, int tid, int w, int l,
                                     int lm, int lk,
                                     const ushort* __restrict__ xb,
                                     const float* cvb,
                                     const ushort* __restrict__ wdts,
                                     float* __restrict__ out, int br_off,
                                     int b, int rem0, float* sred) {
  constexpr int KK = K * K;
  f32x4 acc[4];
#pragma unroll
  for (int j = 0; j < 4; ++j) acc[j] = f32x4{0.f, 0.f, 0.f, 0.f};
#pragma unroll 1
  for (int tt = 0; tt < cnt; ++tt) {
    int t = base + tt;
    float py = cvb[t * 17 + lm];
    float px = cvb[KK * 17 + t * 17 + lm];
    float m = cvb[2 * KK * 17 + t * 17 + lm];
    float fy = floorf(py), fx = floorf(px);
    float wy1 = py - fy, wx1 = px - fx;
    float wy0 = 1.f - wy1, wx0 = 1.f - wx1;
    int y0 = (int)fy, x0 = (int)fx;
    int y1 = y0 + 1, x1 = x0 + 1;
    bool vy0 = (unsigned)y0 < (unsigned)H, vy1 = (unsigned)y1 < (unsigned)H;
    bool vx0 = (unsigned)x0 < (unsigned)W, vx1 = (unsigned)x1 < (unsigned)W;
    float c00s = m * wy0 * wx0 * ((vy0 & vx0) ? 1.f : 0.f);
    float c01s = m * wy0 * wx1 * ((vy0 & vx1) ? 1.f : 0.f);
    float c10s = m * wy1 * wx0 * ((vy1 & vx0) ? 1.f : 0.f);
    float c11s = m * wy1 * wx1 * ((vy1 & vx1) ? 1.f : 0.f);
    f32x2 c00 = f32x2{c00s, c00s}, c01 = f32x2{c01s, c01s};
    f32x2 c10 = f32x2{c10s, c10s}, c11 = f32x2{c11s, c11s};
    int y0c = min(max(y0, 0), H - 1), y1c = min(max(y1, 0), H - 1);
    int x0c = min(max(x0, 0), W - 1), x1c = min(max(x1, 0), W - 1);
    int i00 = (y0c * W + x0c) * C + lk * 8, i01 = (y0c * W + x1c) * C + lk * 8;
    int i10 = (y1c * W + x0c) * C + lk * 8, i11 = (y1c * W + x1c) * C + lk * 8;
    uint4 U0 = *(const uint4*)(xb + i00);
    uint4 U1 = *(const uint4*)(xb + i00 + 32);
    uint4 U2 = *(const uint4*)(xb + i01);
    uint4 U3 = *(const uint4*)(xb + i01 + 32);
    uint4 U4 = *(const uint4*)(xb + i10);
    uint4 U5 = *(const uint4*)(xb + i10 + 32);
    uint4 U6 = *(const uint4*)(xb + i11);
    uint4 U7 = *(const uint4*)(xb + i11 + 32);
    uint4 apa, apb;
    apa.x = bilin_pack(U0.x, U2.x, U4.x, U6.x, c00, c01, c10, c11);
    apa.y = bilin_pack(U0.y, U2.y, U4.y, U6.y, c00, c01, c10, c11);
    apa.z = bilin_pack(U0.z, U2.z, U4.z, U6.z, c00, c01, c10, c11);
    apa.w = bilin_pack(U0.w, U2.w, U4.w, U6.w, c00, c01, c10, c11);
    apb.x = bilin_pack(U1.x, U3.x, U5.x, U7.x, c00, c01, c10, c11);
    apb.y = bilin_pack(U1.y, U3.y, U5.y, U7.y, c00, c01, c10, c11);
    apb.z = bilin_pack(U1.z, U3.z, U5.z, U7.z, c00, c01, c10, c11);
    apb.w = bilin_pack(U1.w, U3.w, U5.w, U7.w, c00, c01, c10, c11);
    short8 aa = *(short8*)&apa;
    short8 ab = *(short8*)&apb;
    const ushort* fb0 = wdts + (size_t)((t * 2 + 0) * 4) * 512 + l * 8;
    const ushort* fb1 = wdts + (size_t)((t * 2 + 1) * 4) * 512 + l * 8;
#pragma unroll
    for (int j = 0; j < 4; ++j) {
      short8 bf = *(const short8*)(fb0 + j * 512);
      acc[j] = __builtin_amdgcn_mfma_f32_16x16x32_bf16(aa, bf, acc[j], 0, 0, 0);
    }
#pragma unroll
    for (int j = 0; j < 4; ++j) {
      short8 bf = *(const short8*)(fb1 + j * 512);
      acc[j] = __builtin_amdgcn_mfma_f32_16x16x32_bf16(ab, bf, acc[j], 0, 0, 0);
    }
  }
  // K-split reduction across the 4 waves (sred aliases the dead window).
  float (*s4)[16][65] = (float (*)[16][65])sred;
#pragma unroll
  for (int j = 0; j < 4; ++j)
#pragma unroll
    for (int r = 0; r < 4; ++r)
      s4[w][lk * 4 + r][j * 16 + lm] = acc[j][r];
  __syncthreads();
#pragma unroll
  for (int i = 0; i < 4; ++i) {
    int idx = i * 256 + tid;
    int mrow = idx & 15, co = idx >> 4;
    float v = s4[0][mrow][co] + s4[1][mrow][co] + s4[2][mrow][co] +
              s4[3][mrow][co];
    out[(size_t)(b * (3 * COUT) + br_off + co) * HW + rem0 + mrow] = v;
  }
  __syncthreads();
}

// ---------------------------------------------------------------------------
// fused_all: one block = 16 pixels (one row segment). Phase A: stage the
// 7x24 input window once (covers k5/k3 windows too), conv all 3 branches,
// offsets/mask straight to LDS (no global round-trip). Phase B: all 3 dcn
// branches, tap-split exactly across waves. LDS: [window|s_red 21504B][cv
// planes 16932B] = 38436B -> 4 blocks/CU.
// ---------------------------------------------------------------------------
__global__ __launch_bounds__(256, 4) void fused_all(
    const ushort* __restrict__ xhb,
    const ushort* __restrict__ wtbs7, const float* __restrict__ bc7,
    const ushort* __restrict__ wdts7,
    const ushort* __restrict__ wtbs5, const float* __restrict__ bc5,
    const ushort* __restrict__ wdts5,
    const ushort* __restrict__ wtbs3, const float* __restrict__ bc3,
    const ushort* __restrict__ wdts3,
    float* __restrict__ out) {
  __shared__ float smem[9612];           // 38448 B
  ushort* win = (ushort*)smem;           // [0,21504): window / s_red union
  float* cv7 = smem + 5376;              // 3*49*17 = 2499 floats
  float* cv5 = cv7 + 2499;               // 3*25*17 = 1275
  float* cv3 = cv5 + 1275;               // 3*9*17  = 459

  int blk = blockIdx.x;
  int tid = threadIdx.x, w = tid >> 6, l = tid & 63;
  int lm = l & 15, lk = l >> 4;
  int m0 = blk * 16;
  int b = m0 / HW;
  int rem0 = m0 - b * HW;
  int y = rem0 / W, x0 = rem0 % W;       // 16 | W -> one row segment
  int xs = x0 - 4;
  const ushort* zsrc = xhb + (size_t)B * HW * C;

  // ---- stage 7x24 window (XOR-preswizzled source, zero-redirect OOB)
  for (int i = w; i < 21; i += 4) {
    int r = i / 3, sgm = i % 3;
    int gy = y - 3 + r;
    int px = xs + sgm * 8 + (l >> 3);
    bool v = ((unsigned)gy < (unsigned)H) && ((unsigned)px < (unsigned)W);
    int slot = (l & 7) ^ ((4 + (l >> 3)) & 7);
    const ushort* src = v ? (xhb + ((size_t)b * HW + gy * W + px) * C + slot * 8)
                          : (zsrc + l * 8);
    gload_lds16(src, win + (r * 24 + sgm * 8) * 64);
  }
  asm volatile("s_waitcnt vmcnt(0)" ::: "memory");
  __syncthreads();

  // ---- phase A: conv, 17 N-tiles split across 4 waves (~equal tap*tile work)
  if (w == 0) {
    convA<7, 10, 3>(0, 3, y, x0, l, lm, lk, win, wtbs7, bc7, cv7);
    convA<3, 2, 1>(0, 1, y, x0, l, lm, lk, win, wtbs3, bc3, cv3);
  } else if (w == 1) {
    convA<7, 10, 3>(3, 3, y, x0, l, lm, lk, win, wtbs7, bc7, cv7);
    convA<3, 2, 1>(1, 1, y, x0, l, lm, lk, win, wtbs3, bc3, cv3);
  } else if (w == 2) {
    convA<7, 10, 4>(6, 4, y, x0, l, lm, lk, win, wtbs7, bc7, cv7);
  } else {
    convA<5, 6, 5>(0, 5, y, x0, l, lm, lk, win, wtbs5, bc5, cv5);
  }
  __syncthreads();                       // cv complete; window now dead

  // ---- phase B: dcn, exact tap splits (no dummy taps)
  const ushort* xb = xhb + (size_t)b * HW * C;
  {
    const int bs7[4] = {0, 13, 25, 37}, cn7[4] = {13, 12, 12, 12};
    dcnB<7>(bs7[w], cn7[w], tid, w, l, lm, lk, xb, cv7, wdts7, out, 128, b,
            rem0, smem);
    const int bs5[4] = {0, 7, 13, 19}, cn5[4] = {7, 6, 6, 6};
    dcnB<5>(bs5[w], cn5[w], tid, w, l, lm, lk, xb, cv5, wdts5, out, 64, b,
            rem0, smem);
    const int bs3[4] = {0, 3, 5, 7}, cn3[4] = {3, 2, 2, 2};
    dcnB<3>(bs3[w], cn3[w], tid, w, l, lm, lk, xb, cv3, wdts3, out, 0, b,
            rem0, smem);
  }
}

// ---------------------------------------------------------------------------
// Launch
// ---------------------------------------------------------------------------
extern "C" void kernel_launch(void* const* d_in, const int* in_sizes, int n_in,
                              void* d_out, int out_size, void* d_ws,
                              size_t ws_size, hipStream_t stream) {
  const float* x = (const float*)d_in[0];
  const float* w_off3 = (const float*)d_in[1];
  const float* b_off3 = (const float*)d_in[2];
  const float* w_mask3 = (const float*)d_in[3];
  const float* b_mask3 = (const float*)d_in[4];
  const float* w_dcn3 = (const float*)d_in[5];
  const float* w_off5 = (const float*)d_in[6];
  const float* b_off5 = (const float*)d_in[7];
  const float* w_mask5 = (const float*)d_in[8];
  const float* b_mask5 = (const float*)d_in[9];
  const float* w_dcn5 = (const float*)d_in[10];
  const float* w_off7 = (const float*)d_in[11];
  const float* b_off7 = (const float*)d_in[12];
  const float* w_mask7 = (const float*)d_in[13];
  const float* b_mask7 = (const float*)d_in[14];
  const float* w_dcn7 = (const float*)d_in[15];
  float* out = (float*)d_out;
  float* ws = (float*)d_ws;

  // Workspace layout (float units, 16B aligned); conv planes eliminated.
  size_t off = 0;
  auto alloc = [&](size_t n) {
    size_t p = off;
    off += (n + 3) & ~(size_t)3;
    return ws + p;
  };
  ushort* xhb = (ushort*)alloc((size_t)B * HW * C / 2 + 320);  // +zero region
  ushort* wtbs3 = (ushort*)alloc(9 * 2 * 2 * 512 / 2);
  ushort* wtbs5 = (ushort*)alloc(25 * 2 * 6 * 512 / 2);
  ushort* wtbs7 = (ushort*)alloc(49 * 2 * 10 * 512 / 2);
  float* bc3 = alloc(27);
  float* bc5 = alloc(75);
  float* bc7 = alloc(147);
  ushort* wdts3 = (ushort*)alloc(9 * 2 * 4 * 512 / 2);
  ushort* wdts5 = (ushort*)alloc(25 * 2 * 4 * 512 / 2);
  ushort* wdts7 = (ushort*)alloc(49 * 2 * 4 * 512 / 2);

  // 1) transpose + all weight prep
  setup_all<<<456, 256, 0, stream>>>(
      x, xhb,
      w_off3, b_off3, w_mask3, b_mask3, w_dcn3, wtbs3, bc3, wdts3,
      w_off5, b_off5, w_mask5, b_mask5, w_dcn5, wtbs5, bc5, wdts5,
      w_off7, b_off7, w_mask7, b_mask7, w_dcn7, wtbs7, bc7, wdts7);

  // 2) fused conv + deformable sampling + einsum (one block = 16 pixels)
  fused_all<<<800, 256, 0, stream>>>(xhb, wtbs7, bc7, wdts7, wtbs5, bc5,
                                     wdts5, wtbs3, bc3, wdts3, out);
}

// Round 8
// 203.244 us; speedup vs baseline: 1.3428x; 1.3428x over previous
//
#include <hip/hip_runtime.h>
#include <math.h>

constexpr int B = 2, C = 64, H = 80, W = 80, HW = H * W, COUT = 64;
constexpr int NPIX = B * HW;   // 12800

typedef __attribute__((ext_vector_type(8))) short short8;   // 8 bf16
typedef __attribute__((ext_vector_type(4))) float f32x4;
typedef __attribute__((ext_vector_type(2))) float f32x2;

__device__ inline ushort f2bf(float f) {
  unsigned u = __float_as_uint(f);
  unsigned r = u + 0x7fff + ((u >> 16) & 1);   // RNE
  return (ushort)(r >> 16);
}

__device__ inline f32x2 unpack_bf2(unsigned u) {
  f32x2 r;
  r.x = __uint_as_float(u << 16);
  r.y = __uint_as_float(u & 0xffff0000u);
  return r;
}

// bilinear-combine 2 bf16 channels x 4 corners, repack to 2 bf16 (1 v_perm)
__device__ inline unsigned bilin_pack(unsigned a, unsigned b, unsigned c,
                                      unsigned d, f32x2 c00, f32x2 c01,
                                      f32x2 c10, f32x2 c11) {
  f32x2 p = unpack_bf2(a) * c00;
  p += unpack_bf2(b) * c01;
  p += unpack_bf2(c) * c10;
  p += unpack_bf2(d) * c11;
  unsigned lo = __float_as_uint(p.x) + 0x8000u;
  unsigned hi = __float_as_uint(p.y) + 0x8000u;
  return __builtin_amdgcn_perm(hi, lo, 0x07060302);
}

// global -> LDS DMA, 16B per lane, linear dest (wave-uniform base + lane*16)
__device__ __forceinline__ void gload_lds16(const ushort* g, ushort* s) {
  __builtin_amdgcn_global_load_lds(
      (const __attribute__((address_space(1))) void*)g,
      (__attribute__((address_space(3))) void*)s, 16, 0, 0);
}

// ---------------------------------------------------------------------------
// Weight prep body (grid-stride over this branch's swizzled tables).
// ---------------------------------------------------------------------------
template <int K, int NT>
__device__ void prep_body(int pb, int nblk, const float* __restrict__ w_off,
                          const float* __restrict__ b_off,
                          const float* __restrict__ w_mask,
                          const float* __restrict__ b_mask,
                          const float* __restrict__ w_dcn,
                          ushort* __restrict__ wtbs, float* __restrict__ bcomb,
                          ushort* __restrict__ wdts) {
  constexpr int KK = K * K, C3 = 3 * KK;
  const int n1 = KK * 2 * NT * 512;
  const int n2 = C3;
  const int n3 = KK * 2 * 4 * 512;
  const int total = n1 + n2 + n3;
  for (int i = pb * 256 + threadIdx.x; i < total; i += nblk * 256) {
    if (i < n1) {
      int e = i & 7, l = (i >> 3) & 63;
      int blk512 = i >> 9;
      int nt = blk512 % NT, th = blk512 / NT;
      int half = th & 1, t = th >> 1;
      int n = nt * 16 + (l & 15);
      int ci = half * 32 + (l >> 4) * 8 + e;
      float v = 0.f;
      if (n < 2 * KK) v = w_off[(n * C + ci) * KK + t];
      else if (n < C3) v = w_mask[((n - 2 * KK) * C + ci) * KK + t];
      wtbs[i] = f2bf(v);
    } else if (i < n1 + n2) {
      int co = i - n1;
      bcomb[co] = (co < 2 * KK) ? b_off[co] : b_mask[co - 2 * KK];
    } else {
      int j = i - n1 - n2;
      int e = j & 7, l = (j >> 3) & 63;
      int blk512 = j >> 9;
      int jt = blk512 & 3, th = blk512 >> 2;
      int half = th & 1, t = th >> 1;
      int co = jt * 16 + (l & 15);
      int ci = half * 32 + (l >> 4) * 8 + e;
      wdts[j] = f2bf(w_dcn[(co * C + ci) * KK + t]);
    }
  }
}

// ---------------------------------------------------------------------------
// setup_all: blocks 0..199 transpose NCHW->NHWC bf16 (+zero region for OOB
// staging redirects); rest weight prep. (k5 table now NT=5 — tile 6 was pure
// zero padding.)
// ---------------------------------------------------------------------------
__global__ __launch_bounds__(256) void setup_all(
    const float* __restrict__ x, ushort* __restrict__ xhb,
    const float* __restrict__ w_off3, const float* __restrict__ b_off3,
    const float* __restrict__ w_mask3, const float* __restrict__ b_mask3,
    const float* __restrict__ w_dcn3, ushort* __restrict__ wtbs3,
    float* __restrict__ bc3, ushort* __restrict__ wdts3,
    const float* __restrict__ w_off5, const float* __restrict__ b_off5,
    const float* __restrict__ w_mask5, const float* __restrict__ b_mask5,
    const float* __restrict__ w_dcn5, ushort* __restrict__ wtbs5,
    float* __restrict__ bc5, ushort* __restrict__ wdts5,
    const float* __restrict__ w_off7, const float* __restrict__ b_off7,
    const float* __restrict__ w_mask7, const float* __restrict__ b_mask7,
    const float* __restrict__ w_dcn7, ushort* __restrict__ wtbs7,
    float* __restrict__ bc7, ushort* __restrict__ wdts7) {
  __shared__ float tile[64][65];
  int blk = blockIdx.x;
  if (blk < 200) {
    int b = blk / (HW / 64);
    int p0 = (blk % (HW / 64)) * 64;
    int lane = threadIdx.x & 63, row = threadIdx.x >> 6;
    if (blk == 0) {                        // 640-ushort zero region
      for (int i = threadIdx.x; i < 640; i += 256)
        xhb[(size_t)B * HW * C + i] = 0;
    }
#pragma unroll
    for (int it = 0; it < 16; ++it) {
      int ci = it * 4 + row;
      tile[ci][lane] = x[(size_t)(b * C + ci) * HW + p0 + lane];
    }
    __syncthreads();
#pragma unroll
    for (int it = 0; it < 16; ++it) {
      int pl = it * 4 + row;
      xhb[((size_t)b * HW + p0 + pl) * C + lane] = f2bf(tile[lane][pl]);
    }
  } else {
    int pb = blk - 200;
    prep_body<7, 10>(pb, 256, w_off7, b_off7, w_mask7, b_mask7, w_dcn7, wtbs7,
                     bc7, wdts7);
    prep_body<5, 5>(pb, 256, w_off5, b_off5, w_mask5, b_mask5, w_dcn5, wtbs5,
                    bc5, wdts5);
    prep_body<3, 2>(pb, 256, w_off3, b_off3, w_mask3, b_mask3, w_dcn3, wtbs3,
                    bc3, wdts3);
  }
}

// ---------------------------------------------------------------------------
// Conv body v3 (batch-pair LDS window): block = same 16-px row segment in
// BOTH batch images. Stage two K x 24 windows (swizzled source, zero-redirect
// OOB), then each wave computes its N-tiles for both batches from one
// B-fragment load -> B address traffic per pixel halves (B-loads were ~60%
// of conv's TA time). A path bit-identical to the proven R6 window kernel.
// ---------------------------------------------------------------------------
template <int K, int NT, int NMAX>
__device__ __forceinline__ void conv_body32(int blk,
                                            const ushort* __restrict__ xhb,
                                            const ushort* __restrict__ zsrc,
                                            const ushort* __restrict__ wtbs,
                                            const float* __restrict__ bcomb,
                                            float* __restrict__ convout,
                                            ushort* win) {
  constexpr int PAD = K / 2, KK = K * K, C3 = 3 * KK;
  constexpr int WSZ = K * 24 * 64;       // ushorts per window
  int tid = threadIdx.x, w = tid >> 6, l = tid & 63;
  int lm = l & 15, lk = l >> 4;
  int y = blk / 5, x0 = (blk % 5) * 16;  // 400 segments per batch image
  int xs = x0 - 4;                       // xs & 7 == 4

  // ---- stage 2 windows (batch 0 and 1): K rows x 3 chunks each
  for (int i = w; i < 2 * K * 3; i += 4) {
    int wb = i / (K * 3), j = i % (K * 3);
    int r = j / 3, sgm = j % 3;
    int gy = y - PAD + r;
    int px = xs + sgm * 8 + (l >> 3);
    bool v = ((unsigned)gy < (unsigned)H) && ((unsigned)px < (unsigned)W);
    int slot = (l & 7) ^ ((4 + (l >> 3)) & 7);   // px&7 == (4 + (l>>3))&7
    const ushort* src =
        v ? (xhb + ((size_t)wb * HW + gy * W + px) * C + slot * 8)
          : (zsrc + l * 8);
    gload_lds16(src, win + wb * WSZ + (r * 24 + sgm * 8) * 64);
  }
  asm volatile("s_waitcnt vmcnt(0)" ::: "memory");
  __syncthreads();

  // ---- per-wave N-tile assignment (NT tiles total, no padding tiles)
  int j0w, ntw;
  if constexpr (K == 7) {
    const int J0[4] = {0, 3, 6, 8}, NW[4] = {3, 3, 2, 2};
    j0w = J0[w]; ntw = NW[w];
  } else if constexpr (K == 5) {
    const int J0[4] = {0, 2, 3, 4}, NW[4] = {2, 1, 1, 1};
    j0w = J0[w]; ntw = NW[w];
  } else {
    const int J0[4] = {0, 1, 0, 0}, NW[4] = {1, 1, 0, 0};
    j0w = J0[w]; ntw = NW[w];
  }

  f32x4 acc[2][NMAX];
#pragma unroll
  for (int g = 0; g < 2; ++g)
#pragma unroll
    for (int j = 0; j < NMAX; ++j) acc[g][j] = f32x4{0.f, 0.f, 0.f, 0.f};

  short8 Bf0[2][NMAX], Bf1[2][NMAX];
  auto loadB = [&](int t, int s) {
    const ushort* fbase = wtbs + (size_t)(t * 2) * NT * 512 + l * 8;
#pragma unroll
    for (int jj = 0; jj < NMAX; ++jj)
      if (jj < ntw) {
        Bf0[s][jj] = *(const short8*)(fbase + (size_t)(j0w + jj) * 512);
        Bf1[s][jj] = *(const short8*)(fbase + (size_t)(NT + j0w + jj) * 512);
      }
  };

  loadB(0, 0);
#pragma unroll
  for (int t = 0; t < KK; ++t) {
    int s = t & 1;
    if (t + 1 < KK) loadB(t + 1, s ^ 1);
    int ky = t / K, kx = t % K;
    int c = 4 + lm + kx - PAD;           // window col, in [1,23)
    int h = (4 + c) & 7;                 // == global px&7
#pragma unroll
    for (int g = 0; g < 2; ++g) {
      const ushort* ap = win + g * WSZ + (ky * 24 + c) * 64;
      short8 A0v = *(const short8*)(ap + ((lk ^ h) * 8));
      short8 A1v = *(const short8*)(ap + (((lk + 4) ^ h) * 8));
#pragma unroll
      for (int jj = 0; jj < NMAX; ++jj)
        if (jj < ntw)
          acc[g][jj] = __builtin_amdgcn_mfma_f32_16x16x32_bf16(
              A0v, Bf0[s][jj], acc[g][jj], 0, 0, 0);
#pragma unroll
      for (int jj = 0; jj < NMAX; ++jj)
        if (jj < ntw)
          acc[g][jj] = __builtin_amdgcn_mfma_f32_16x16x32_bf16(
              A1v, Bf1[s][jj], acc[g][jj], 0, 0, 0);
    }
  }

  // Epilogue. D mapping: col(n)=lm, row(m)=lk*4+r -> f32x4 plane store.
#pragma unroll
  for (int g = 0; g < 2; ++g) {
#pragma unroll
    for (int jj = 0; jj < NMAX; ++jj) {
      if (jj >= ntw) continue;
      int co = (j0w + jj) * 16 + lm;
      if (co >= C3) continue;            // k=5 tile-4 tail padding
      float bs = bcomb[co];
      bool isoff = co < 2 * KK;
      int tp = isoff ? (co >> 1) : (co - 2 * KK);
      int plane = isoff ? (co & 1) : 2;  // 0=py, 1=px, 2=mask
      f32x4 vv;
#pragma unroll
      for (int r = 0; r < 4; ++r) {
        int xr = x0 + lk * 4 + r;
        float v = acc[g][jj][r] + bs;
        if (isoff) {
          v += (co & 1) ? (float)(xr - PAD + tp % K)    // px
                        : (float)(y - PAD + tp / K);    // py
        } else {
          v = 1.f / (1.f + expf(-v));
        }
        vv[r] = v;
      }
      int pix0 = g * HW + blk * 16 + lk * 4;   // global pixel index
      *(f32x4*)(convout + ((size_t)plane * KK + tp) * NPIX + pix0) = vv;
    }
  }
}

__global__ __launch_bounds__(256, 3) void conv_all(
    const ushort* __restrict__ xhb,
    const ushort* __restrict__ wtbs7, const float* __restrict__ bc7, float* __restrict__ co7,
    const ushort* __restrict__ wtbs5, const float* __restrict__ bc5, float* __restrict__ co5,
    const ushort* __restrict__ wtbs3, const float* __restrict__ bc3, float* __restrict__ co3) {
  __shared__ ushort win[2 * 7 * 24 * 64];   // 43008 B (k=7 pair; others less)
  const ushort* zsrc = xhb + (size_t)B * HW * C;   // 640-ushort zero region
  int blk = blockIdx.x;
  if (blk < 400) conv_body32<7, 10, 3>(blk, xhb, zsrc, wtbs7, bc7, co7, win);
  else if (blk < 800) conv_body32<5, 5, 2>(blk - 400, xhb, zsrc, wtbs5, bc5, co5, win);
  else conv_body32<3, 2, 1>(blk - 800, xhb, zsrc, wtbs3, bc3, co3, win);
}

// ---------------------------------------------------------------------------
// DCN body v6 (unchanged from round 5/6, 85.3us proven): tap-split, M=32 per
// wave; two pixel groups share every B-fragment load; offsets via 32-lane
// loads + shfl distribution.
// ---------------------------------------------------------------------------
template <int K, int TPW>
__device__ __forceinline__ void dcn_body(int blk, const ushort* __restrict__ xhb,
                                         const float* __restrict__ convout,
                                         const ushort* __restrict__ wdts,
                                         float* __restrict__ out, int br_off,
                                         float* smem) {
  constexpr int KK = K * K;
  int tid = threadIdx.x, w = tid >> 6, l = tid & 63;
  int lm = l & 15, lk = l >> 4;
  int m0 = blk * 32;                       // 32 | HW
  int b = m0 / HW;
  const ushort* xb = xhb + (size_t)b * HW * C;
  const float* pyP = convout;
  const float* pxP = convout + (size_t)KK * NPIX;
  const float* mP = convout + (size_t)2 * KK * NPIX;
  const int t0 = w * TPW;

  f32x4 acc[2][4];
#pragma unroll
  for (int g = 0; g < 2; ++g)
#pragma unroll
    for (int j = 0; j < 4; ++j) acc[g][j] = f32x4{0.f, 0.f, 0.f, 0.f};

  // Per-lane staged offset values: lanes 0..31 hold pixel m0+l of the tap.
  float pvy = 0.f, pvx = 0.f, pvm = 0.f;
  auto lofs = [&](int tt) {
    int t = t0 + tt;
    bool tv = t < KK;
    int ts = tv ? t : KK - 1;              // clamp: dummy taps read valid data
    if (l < 32) {
      size_t o = (size_t)ts * NPIX + m0 + l;
      pvy = pyP[o];
      pvx = pxP[o];
      pvm = tv ? mP[o] : 0.f;              // dummy taps contribute exactly 0
    }
  };

  auto sample = [&](float py, float px, float m, uint4 (&U)[8],
                    f32x2 (&CCv)[4]) {
    float fy = floorf(py), fx = floorf(px);
    float wy1 = py - fy, wx1 = px - fx;
    float wy0 = 1.f - wy1, wx0 = 1.f - wx1;
    int y0 = (int)fy, x0 = (int)fx;
    int y1 = y0 + 1, x1 = x0 + 1;
    bool vy0 = (unsigned)y0 < (unsigned)H, vy1 = (unsigned)y1 < (unsigned)H;
    bool vx0 = (unsigned)x0 < (unsigned)W, vx1 = (unsigned)x1 < (unsigned)W;
    float c00s = m * wy0 * wx0 * ((vy0 & vx0) ? 1.f : 0.f);
    float c01s = m * wy0 * wx1 * ((vy0 & vx1) ? 1.f : 0.f);
    float c10s = m * wy1 * wx0 * ((vy1 & vx0) ? 1.f : 0.f);
    float c11s = m * wy1 * wx1 * ((vy1 & vx1) ? 1.f : 0.f);
    CCv[0] = f32x2{c00s, c00s};
    CCv[1] = f32x2{c01s, c01s};
    CCv[2] = f32x2{c10s, c10s};
    CCv[3] = f32x2{c11s, c11s};
    int y0c = min(max(y0, 0), H - 1), y1c = min(max(y1, 0), H - 1);
    int x0c = min(max(x0, 0), W - 1), x1c = min(max(x1, 0), W - 1);
    int i00 = (y0c * W + x0c) * C + lk * 8, i01 = (y0c * W + x1c) * C + lk * 8;
    int i10 = (y1c * W + x0c) * C + lk * 8, i11 = (y1c * W + x1c) * C + lk * 8;
    U[0] = *(const uint4*)(xb + i00);
    U[1] = *(const uint4*)(xb + i00 + 32);
    U[2] = *(const uint4*)(xb + i01);
    U[3] = *(const uint4*)(xb + i01 + 32);
    U[4] = *(const uint4*)(xb + i10);
    U[5] = *(const uint4*)(xb + i10 + 32);
    U[6] = *(const uint4*)(xb + i11);
    U[7] = *(const uint4*)(xb + i11 + 32);
  };

  auto pack2 = [&](uint4 (&U)[8], f32x2 (&CCv)[4], short8& aa, short8& ab) {
    f32x2 c00 = CCv[0], c01 = CCv[1], c10 = CCv[2], c11 = CCv[3];
    uint4 apa, apb;
    apa.x = bilin_pack(U[0].x, U[2].x, U[4].x, U[6].x, c00, c01, c10, c11);
    apa.y = bilin_pack(U[0].y, U[2].y, U[4].y, U[6].y, c00, c01, c10, c11);
    apa.z = bilin_pack(U[0].z, U[2].z, U[4].z, U[6].z, c00, c01, c10, c11);
    apa.w = bilin_pack(U[0].w, U[2].w, U[4].w, U[6].w, c00, c01, c10, c11);
    apb.x = bilin_pack(U[1].x, U[3].x, U[5].x, U[7].x, c00, c01, c10, c11);
    apb.y = bilin_pack(U[1].y, U[3].y, U[5].y, U[7].y, c00, c01, c10, c11);
    apb.z = bilin_pack(U[1].z, U[3].z, U[5].z, U[7].z, c00, c01, c10, c11);
    apb.w = bilin_pack(U[1].w, U[3].w, U[5].w, U[7].w, c00, c01, c10, c11);
    aa = *(short8*)&apa;
    ab = *(short8*)&apb;
  };

  lofs(0);
#pragma unroll
  for (int tt = 0; tt < TPW; ++tt) {
    // distribute staged offsets: group A = pixels m0+lm, B = m0+16+lm
    float pyA = __shfl(pvy, lm), pyB = __shfl(pvy, lm + 16);
    float pxA = __shfl(pvx, lm), pxB = __shfl(pvx, lm + 16);
    float mA = __shfl(pvm, lm), mB = __shfl(pvm, lm + 16);
    int ts = min(t0 + tt, KK - 1);
    if (tt + 1 < TPW) lofs(tt + 1);        // prefetch next tap's offsets

    uint4 UA[8], UB[8];
    f32x2 CA[4], CB[4];
    sample(pyA, pxA, mA, UA, CA);
    sample(pyB, pxB, mB, UB, CB);
    short8 aaA, abA, aaB, abB;
    pack2(UA, CA, aaA, abA);
    pack2(UB, CB, aaB, abB);

    const ushort* fb0 = wdts + (size_t)((ts * 2 + 0) * 4) * 512 + l * 8;
    const ushort* fb1 = wdts + (size_t)((ts * 2 + 1) * 4) * 512 + l * 8;
#pragma unroll
    for (int j = 0; j < 4; ++j) {
      short8 bf = *(const short8*)(fb0 + j * 512);
      acc[0][j] = __builtin_amdgcn_mfma_f32_16x16x32_bf16(aaA, bf, acc[0][j], 0, 0, 0);
      acc[1][j] = __builtin_amdgcn_mfma_f32_16x16x32_bf16(aaB, bf, acc[1][j], 0, 0, 0);
    }
#pragma unroll
    for (int j = 0; j < 4; ++j) {
      short8 bf = *(const short8*)(fb1 + j * 512);
      acc[0][j] = __builtin_amdgcn_mfma_f32_16x16x32_bf16(abA, bf, acc[0][j], 0, 0, 0);
      acc[1][j] = __builtin_amdgcn_mfma_f32_16x16x32_bf16(abB, bf, acc[1][j], 0, 0, 0);
    }
  }

  // K-split reduction across the 4 waves. D map: col=lm(co), row=lk*4+r(pixel).
  float (*s_red)[32][65] = (float (*)[32][65])smem;
#pragma unroll
  for (int g = 0; g < 2; ++g)
#pragma unroll
    for (int j = 0; j < 4; ++j)
#pragma unroll
      for (int r = 0; r < 4; ++r)
        s_red[w][g * 16 + lk * 4 + r][j * 16 + lm] = acc[g][j][r];
  __syncthreads();
  int rem0 = m0 - b * HW;
#pragma unroll
  for (int i = 0; i < 8; ++i) {
    int idx = i * 256 + tid;               // 8192 = 32 pix x 64 co
    int mrow = idx & 31, co = idx >> 5;
    float v = s_red[0][mrow][co] + s_red[1][mrow][co] +
              s_red[2][mrow][co] + s_red[3][mrow][co];
    out[(size_t)(b * (3 * COUT) + br_off + co) * HW + rem0 + mrow] = v;
  }
}

__global__ __launch_bounds__(256, 3) void dcn_all(
    const ushort* __restrict__ xhb,
    const float* __restrict__ co7, const ushort* __restrict__ wdts7,
    const float* __restrict__ co5, const ushort* __restrict__ wdts5,
    const float* __restrict__ co3, const ushort* __restrict__ wdts3,
    float* __restrict__ out) {
  __shared__ float smem[4 * 32 * 65];   // s_red (33.3KB; 3 blocks = 100KB/CU)
  int blk = blockIdx.x;
  if (blk < 400) dcn_body<7, 13>(blk, xhb, co7, wdts7, out, 128, smem);
  else if (blk < 800) dcn_body<5, 7>(blk - 400, xhb, co5, wdts5, out, 64, smem);
  else dcn_body<3, 3>(blk - 800, xhb, co3, wdts3, out, 0, smem);
}

// ---------------------------------------------------------------------------
// Launch
// ---------------------------------------------------------------------------
extern "C" void kernel_launch(void* const* d_in, const int* in_sizes, int n_in,
                              void* d_out, int out_size, void* d_ws,
                              size_t ws_size, hipStream_t stream) {
  const float* x = (const float*)d_in[0];
  const float* w_off3 = (const float*)d_in[1];
  const float* b_off3 = (const float*)d_in[2];
  const float* w_mask3 = (const float*)d_in[3];
  const float* b_mask3 = (const float*)d_in[4];
  const float* w_dcn3 = (const float*)d_in[5];
  const float* w_off5 = (const float*)d_in[6];
  const float* b_off5 = (const float*)d_in[7];
  const float* w_mask5 = (const float*)d_in[8];
  const float* b_mask5 = (const float*)d_in[9];
  const float* w_dcn5 = (const float*)d_in[10];
  const float* w_off7 = (const float*)d_in[11];
  const float* b_off7 = (const float*)d_in[12];
  const float* w_mask7 = (const float*)d_in[13];
  const float* b_mask7 = (const float*)d_in[14];
  const float* w_dcn7 = (const float*)d_in[15];
  float* out = (float*)d_out;
  float* ws = (float*)d_ws;

  // Workspace layout (float units, 16B aligned)
  size_t off = 0;
  auto alloc = [&](size_t n) {
    size_t p = off;
    off += (n + 3) & ~(size_t)3;
    return ws + p;
  };
  ushort* xhb = (ushort*)alloc((size_t)B * HW * C / 2 + 320);  // +zero region
  float* co3 = alloc((size_t)B * HW * 27);
  float* co5 = alloc((size_t)B * HW * 75);
  float* co7 = alloc((size_t)B * HW * 147);
  ushort* wtbs3 = (ushort*)alloc(9 * 2 * 2 * 512 / 2);
  ushort* wtbs5 = (ushort*)alloc(25 * 2 * 5 * 512 / 2);
  ushort* wtbs7 = (ushort*)alloc(49 * 2 * 10 * 512 / 2);
  float* bc3 = alloc(27);
  float* bc5 = alloc(75);
  float* bc7 = alloc(147);
  ushort* wdts3 = (ushort*)alloc(9 * 2 * 4 * 512 / 2);
  ushort* wdts5 = (ushort*)alloc(25 * 2 * 4 * 512 / 2);
  ushort* wdts7 = (ushort*)alloc(49 * 2 * 4 * 512 / 2);

  // 1) transpose + all weight prep (one launch)
  setup_all<<<456, 256, 0, stream>>>(
      x, xhb,
      w_off3, b_off3, w_mask3, b_mask3, w_dcn3, wtbs3, bc3, wdts3,
      w_off5, b_off5, w_mask5, b_mask5, w_dcn5, wtbs5, bc5, wdts5,
      w_off7, b_off7, w_mask7, b_mask7, w_dcn7, wtbs7, bc7, wdts7);

  // 2) all offset+mask convs (batch-pair windows; 400 blocks per branch)
  conv_all<<<1200, 256, 0, stream>>>(xhb, wtbs7, bc7, co7, wtbs5, bc5, co5,
                                     wtbs3, bc3, co3);

  // 3) all fused deformable sampling + einsum (tap-split, M=32/wave)
  dcn_all<<<1200, 256, 0, stream>>>(xhb, co7, wdts7, co5, wdts5, co3, wdts3,
                                    out);
}

// Round 9
// 196.009 us; speedup vs baseline: 1.3924x; 1.0369x over previous
//
#include <hip/hip_runtime.h>
#include <math.h>

constexpr int B = 2, C = 64, H = 80, W = 80, HW = H * W, COUT = 64;
constexpr int NPIX = B * HW;   // 12800

typedef __attribute__((ext_vector_type(8))) short short8;   // 8 bf16
typedef __attribute__((ext_vector_type(4))) float f32x4;
typedef __attribute__((ext_vector_type(2))) float f32x2;

__device__ inline ushort f2bf(float f) {
  unsigned u = __float_as_uint(f);
  unsigned r = u + 0x7fff + ((u >> 16) & 1);   // RNE
  return (ushort)(r >> 16);
}

__device__ inline f32x2 unpack_bf2(unsigned u) {
  f32x2 r;
  r.x = __uint_as_float(u << 16);
  r.y = __uint_as_float(u & 0xffff0000u);
  return r;
}

// bilinear-combine 2 bf16 channels x 4 corners, repack to 2 bf16 (1 v_perm)
__device__ inline unsigned bilin_pack(unsigned a, unsigned b, unsigned c,
                                      unsigned d, f32x2 c00, f32x2 c01,
                                      f32x2 c10, f32x2 c11) {
  f32x2 p = unpack_bf2(a) * c00;
  p += unpack_bf2(b) * c01;
  p += unpack_bf2(c) * c10;
  p += unpack_bf2(d) * c11;
  unsigned lo = __float_as_uint(p.x) + 0x8000u;
  unsigned hi = __float_as_uint(p.y) + 0x8000u;
  return __builtin_amdgcn_perm(hi, lo, 0x07060302);
}

// global -> LDS DMA, 16B per lane, linear dest (wave-uniform base + lane*16)
__device__ __forceinline__ void gload_lds16(const ushort* g, ushort* s) {
  __builtin_amdgcn_global_load_lds(
      (const __attribute__((address_space(1))) void*)g,
      (__attribute__((address_space(3))) void*)s, 16, 0, 0);
}

// ---------------------------------------------------------------------------
// Weight prep body (grid-stride over this branch's swizzled tables).
// ---------------------------------------------------------------------------
template <int K, int NT>
__device__ void prep_body(int pb, int nblk, const float* __restrict__ w_off,
                          const float* __restrict__ b_off,
                          const float* __restrict__ w_mask,
                          const float* __restrict__ b_mask,
                          const float* __restrict__ w_dcn,
                          ushort* __restrict__ wtbs, float* __restrict__ bcomb,
                          ushort* __restrict__ wdts) {
  constexpr int KK = K * K, C3 = 3 * KK;
  const int n1 = KK * 2 * NT * 512;
  const int n2 = C3;
  const int n3 = KK * 2 * 4 * 512;
  const int total = n1 + n2 + n3;
  for (int i = pb * 256 + threadIdx.x; i < total; i += nblk * 256) {
    if (i < n1) {
      int e = i & 7, l = (i >> 3) & 63;
      int blk512 = i >> 9;
      int nt = blk512 % NT, th = blk512 / NT;
      int half = th & 1, t = th >> 1;
      int n = nt * 16 + (l & 15);
      int ci = half * 32 + (l >> 4) * 8 + e;
      float v = 0.f;
      if (n < 2 * KK) v = w_off[(n * C + ci) * KK + t];
      else if (n < C3) v = w_mask[((n - 2 * KK) * C + ci) * KK + t];
      wtbs[i] = f2bf(v);
    } else if (i < n1 + n2) {
      int co = i - n1;
      bcomb[co] = (co < 2 * KK) ? b_off[co] : b_mask[co - 2 * KK];
    } else {
      int j = i - n1 - n2;
      int e = j & 7, l = (j >> 3) & 63;
      int blk512 = j >> 9;
      int jt = blk512 & 3, th = blk512 >> 2;
      int half = th & 1, t = th >> 1;
      int co = jt * 16 + (l & 15);
      int ci = half * 32 + (l >> 4) * 8 + e;
      wdts[j] = f2bf(w_dcn[(co * C + ci) * KK + t]);
    }
  }
}

// ---------------------------------------------------------------------------
// setup_all: blocks 0..199 transpose NCHW->NHWC bf16 (+zero region for OOB
// staging redirects); rest weight prep. (k5 conv table NT=5.)
// ---------------------------------------------------------------------------
__global__ __launch_bounds__(256) void setup_all(
    const float* __restrict__ x, ushort* __restrict__ xhb,
    const float* __restrict__ w_off3, const float* __restrict__ b_off3,
    const float* __restrict__ w_mask3, const float* __restrict__ b_mask3,
    const float* __restrict__ w_dcn3, ushort* __restrict__ wtbs3,
    float* __restrict__ bc3, ushort* __restrict__ wdts3,
    const float* __restrict__ w_off5, const float* __restrict__ b_off5,
    const float* __restrict__ w_mask5, const float* __restrict__ b_mask5,
    const float* __restrict__ w_dcn5, ushort* __restrict__ wtbs5,
    float* __restrict__ bc5, ushort* __restrict__ wdts5,
    const float* __restrict__ w_off7, const float* __restrict__ b_off7,
    const float* __restrict__ w_mask7, const float* __restrict__ b_mask7,
    const float* __restrict__ w_dcn7, ushort* __restrict__ wtbs7,
    float* __restrict__ bc7, ushort* __restrict__ wdts7) {
  __shared__ float tile[64][65];
  int blk = blockIdx.x;
  if (blk < 200) {
    int b = blk / (HW / 64);
    int p0 = (blk % (HW / 64)) * 64;
    int lane = threadIdx.x & 63, row = threadIdx.x >> 6;
    if (blk == 0) {                        // 640-ushort zero region
      for (int i = threadIdx.x; i < 640; i += 256)
        xhb[(size_t)B * HW * C + i] = 0;
    }
#pragma unroll
    for (int it = 0; it < 16; ++it) {
      int ci = it * 4 + row;
      tile[ci][lane] = x[(size_t)(b * C + ci) * HW + p0 + lane];
    }
    __syncthreads();
#pragma unroll
    for (int it = 0; it < 16; ++it) {
      int pl = it * 4 + row;
      xhb[((size_t)b * HW + p0 + pl) * C + lane] = f2bf(tile[lane][pl]);
    }
  } else {
    int pb = blk - 200;
    prep_body<7, 10>(pb, 256, w_off7, b_off7, w_mask7, b_mask7, w_dcn7, wtbs7,
                     bc7, wdts7);
    prep_body<5, 5>(pb, 256, w_off5, b_off5, w_mask5, b_mask5, w_dcn5, wtbs5,
                    bc5, wdts5);
    prep_body<3, 2>(pb, 256, w_off3, b_off3, w_mask3, b_mask3, w_dcn3, wtbs3,
                    bc3, wdts3);
  }
}

// ---------------------------------------------------------------------------
// Conv body v3 (batch-pair LDS window, unchanged from R8 — proven ~32us):
// block = same 16-px row segment in BOTH batch images; one B-fragment load
// serves both batches.
// ---------------------------------------------------------------------------
template <int K, int NT, int NMAX>
__device__ __forceinline__ void conv_body32(int blk,
                                            const ushort* __restrict__ xhb,
                                            const ushort* __restrict__ zsrc,
                                            const ushort* __restrict__ wtbs,
                                            const float* __restrict__ bcomb,
                                            float* __restrict__ convout,
                                            ushort* win) {
  constexpr int PAD = K / 2, KK = K * K, C3 = 3 * KK;
  constexpr int WSZ = K * 24 * 64;       // ushorts per window
  int tid = threadIdx.x, w = tid >> 6, l = tid & 63;
  int lm = l & 15, lk = l >> 4;
  int y = blk / 5, x0 = (blk % 5) * 16;  // 400 segments per batch image
  int xs = x0 - 4;                       // xs & 7 == 4

  // ---- stage 2 windows (batch 0 and 1): K rows x 3 chunks each
  for (int i = w; i < 2 * K * 3; i += 4) {
    int wb = i / (K * 3), j = i % (K * 3);
    int r = j / 3, sgm = j % 3;
    int gy = y - PAD + r;
    int px = xs + sgm * 8 + (l >> 3);
    bool v = ((unsigned)gy < (unsigned)H) && ((unsigned)px < (unsigned)W);
    int slot = (l & 7) ^ ((4 + (l >> 3)) & 7);   // px&7 == (4 + (l>>3))&7
    const ushort* src =
        v ? (xhb + ((size_t)wb * HW + gy * W + px) * C + slot * 8)
          : (zsrc + l * 8);
    gload_lds16(src, win + wb * WSZ + (r * 24 + sgm * 8) * 64);
  }
  asm volatile("s_waitcnt vmcnt(0)" ::: "memory");
  __syncthreads();

  // ---- per-wave N-tile assignment (NT tiles total, no padding tiles)
  int j0w, ntw;
  if constexpr (K == 7) {
    const int J0[4] = {0, 3, 6, 8}, NW[4] = {3, 3, 2, 2};
    j0w = J0[w]; ntw = NW[w];
  } else if constexpr (K == 5) {
    const int J0[4] = {0, 2, 3, 4}, NW[4] = {2, 1, 1, 1};
    j0w = J0[w]; ntw = NW[w];
  } else {
    const int J0[4] = {0, 1, 0, 0}, NW[4] = {1, 1, 0, 0};
    j0w = J0[w]; ntw = NW[w];
  }

  f32x4 acc[2][NMAX];
#pragma unroll
  for (int g = 0; g < 2; ++g)
#pragma unroll
    for (int j = 0; j < NMAX; ++j) acc[g][j] = f32x4{0.f, 0.f, 0.f, 0.f};

  short8 Bf0[2][NMAX], Bf1[2][NMAX];
  auto loadB = [&](int t, int s) {
    const ushort* fbase = wtbs + (size_t)(t * 2) * NT * 512 + l * 8;
#pragma unroll
    for (int jj = 0; jj < NMAX; ++jj)
      if (jj < ntw) {
        Bf0[s][jj] = *(const short8*)(fbase + (size_t)(j0w + jj) * 512);
        Bf1[s][jj] = *(const short8*)(fbase + (size_t)(NT + j0w + jj) * 512);
      }
  };

  loadB(0, 0);
#pragma unroll
  for (int t = 0; t < KK; ++t) {
    int s = t & 1;
    if (t + 1 < KK) loadB(t + 1, s ^ 1);
    int ky = t / K, kx = t % K;
    int c = 4 + lm + kx - PAD;           // window col, in [1,23)
    int h = (4 + c) & 7;                 // == global px&7
#pragma unroll
    for (int g = 0; g < 2; ++g) {
      const ushort* ap = win + g * WSZ + (ky * 24 + c) * 64;
      short8 A0v = *(const short8*)(ap + ((lk ^ h) * 8));
      short8 A1v = *(const short8*)(ap + (((lk + 4) ^ h) * 8));
#pragma unroll
      for (int jj = 0; jj < NMAX; ++jj)
        if (jj < ntw)
          acc[g][jj] = __builtin_amdgcn_mfma_f32_16x16x32_bf16(
              A0v, Bf0[s][jj], acc[g][jj], 0, 0, 0);
#pragma unroll
      for (int jj = 0; jj < NMAX; ++jj)
        if (jj < ntw)
          acc[g][jj] = __builtin_amdgcn_mfma_f32_16x16x32_bf16(
              A1v, Bf1[s][jj], acc[g][jj], 0, 0, 0);
    }
  }

  // Epilogue. D mapping: col(n)=lm, row(m)=lk*4+r -> f32x4 plane store.
#pragma unroll
  for (int g = 0; g < 2; ++g) {
#pragma unroll
    for (int jj = 0; jj < NMAX; ++jj) {
      if (jj >= ntw) continue;
      int co = (j0w + jj) * 16 + lm;
      if (co >= C3) continue;            // k=5 tile-4 tail padding
      float bs = bcomb[co];
      bool isoff = co < 2 * KK;
      int tp = isoff ? (co >> 1) : (co - 2 * KK);
      int plane = isoff ? (co & 1) : 2;  // 0=py, 1=px, 2=mask
      f32x4 vv;
#pragma unroll
      for (int r = 0; r < 4; ++r) {
        int xr = x0 + lk * 4 + r;
        float v = acc[g][jj][r] + bs;
        if (isoff) {
          v += (co & 1) ? (float)(xr - PAD + tp % K)    // px
                        : (float)(y - PAD + tp / K);    // py
        } else {
          v = 1.f / (1.f + expf(-v));
        }
        vv[r] = v;
      }
      int pix0 = g * HW + blk * 16 + lk * 4;   // global pixel index
      *(f32x4*)(convout + ((size_t)plane * KK + tp) * NPIX + pix0) = vv;
    }
  }
}

__global__ __launch_bounds__(256, 3) void conv_all(
    const ushort* __restrict__ xhb,
    const ushort* __restrict__ wtbs7, const float* __restrict__ bc7, float* __restrict__ co7,
    const ushort* __restrict__ wtbs5, const float* __restrict__ bc5, float* __restrict__ co5,
    const ushort* __restrict__ wtbs3, const float* __restrict__ bc3, float* __restrict__ co3) {
  __shared__ ushort win[2 * 7 * 24 * 64];   // 43008 B (k=7 pair; others less)
  const ushort* zsrc = xhb + (size_t)B * HW * C;   // 640-ushort zero region
  int blk = blockIdx.x;
  if (blk < 400) conv_body32<7, 10, 3>(blk, xhb, zsrc, wtbs7, bc7, co7, win);
  else if (blk < 800) conv_body32<5, 5, 2>(blk - 400, xhb, zsrc, wtbs5, bc5, co5, win);
  else conv_body32<3, 2, 1>(blk - 800, xhb, zsrc, wtbs3, bc3, co3, win);
}

// ---------------------------------------------------------------------------
// DCN v7: M=32 tap-split with EXACT per-wave tap ranges via per-wave template
// instantiation (compile-time CNT keeps full unrolling; no dummy taps — they
// were 9.8% of all wave-taps and ran the full gather+MFMA pipeline for +0.0).
// Bit-identical accumulation (dummies contributed exact zero).
// ---------------------------------------------------------------------------
__device__ __forceinline__ void dcn_sample(float py, float px, float m,
                                           const ushort* __restrict__ xb,
                                           int lk, uint4 (&U)[8],
                                           f32x2 (&CCv)[4]) {
  float fy = floorf(py), fx = floorf(px);
  float wy1 = py - fy, wx1 = px - fx;
  float wy0 = 1.f - wy1, wx0 = 1.f - wx1;
  int y0 = (int)fy, x0 = (int)fx;
  int y1 = y0 + 1, x1 = x0 + 1;
  bool vy0 = (unsigned)y0 < (unsigned)H, vy1 = (unsigned)y1 < (unsigned)H;
  bool vx0 = (unsigned)x0 < (unsigned)W, vx1 = (unsigned)x1 < (unsigned)W;
  float c00s = m * wy0 * wx0 * ((vy0 & vx0) ? 1.f : 0.f);
  float c01s = m * wy0 * wx1 * ((vy0 & vx1) ? 1.f : 0.f);
  float c10s = m * wy1 * wx0 * ((vy1 & vx0) ? 1.f : 0.f);
  float c11s = m * wy1 * wx1 * ((vy1 & vx1) ? 1.f : 0.f);
  CCv[0] = f32x2{c00s, c00s};
  CCv[1] = f32x2{c01s, c01s};
  CCv[2] = f32x2{c10s, c10s};
  CCv[3] = f32x2{c11s, c11s};
  int y0c = min(max(y0, 0), H - 1), y1c = min(max(y1, 0), H - 1);
  int x0c = min(max(x0, 0), W - 1), x1c = min(max(x1, 0), W - 1);
  int i00 = (y0c * W + x0c) * C + lk * 8, i01 = (y0c * W + x1c) * C + lk * 8;
  int i10 = (y1c * W + x0c) * C + lk * 8, i11 = (y1c * W + x1c) * C + lk * 8;
  U[0] = *(const uint4*)(xb + i00);
  U[1] = *(const uint4*)(xb + i00 + 32);
  U[2] = *(const uint4*)(xb + i01);
  U[3] = *(const uint4*)(xb + i01 + 32);
  U[4] = *(const uint4*)(xb + i10);
  U[5] = *(const uint4*)(xb + i10 + 32);
  U[6] = *(const uint4*)(xb + i11);
  U[7] = *(const uint4*)(xb + i11 + 32);
}

__device__ __forceinline__ void dcn_pack2(const uint4 (&U)[8],
                                          const f32x2 (&CCv)[4], short8& aa,
                                          short8& ab) {
  f32x2 c00 = CCv[0], c01 = CCv[1], c10 = CCv[2], c11 = CCv[3];
  uint4 apa, apb;
  apa.x = bilin_pack(U[0].x, U[2].x, U[4].x, U[6].x, c00, c01, c10, c11);
  apa.y = bilin_pack(U[0].y, U[2].y, U[4].y, U[6].y, c00, c01, c10, c11);
  apa.z = bilin_pack(U[0].z, U[2].z, U[4].z, U[6].z, c00, c01, c10, c11);
  apa.w = bilin_pack(U[0].w, U[2].w, U[4].w, U[6].w, c00, c01, c10, c11);
  apb.x = bilin_pack(U[1].x, U[3].x, U[5].x, U[7].x, c00, c01, c10, c11);
  apb.y = bilin_pack(U[1].y, U[3].y, U[5].y, U[7].y, c00, c01, c10, c11);
  apb.z = bilin_pack(U[1].z, U[3].z, U[5].z, U[7].z, c00, c01, c10, c11);
  apb.w = bilin_pack(U[1].w, U[3].w, U[5].w, U[7].w, c00, c01, c10, c11);
  aa = *(short8*)&apa;
  ab = *(short8*)&apb;
}

template <int K, int CNT>
__device__ __forceinline__ void dcn_taps(int base, int l, int lm, int lk,
                                         int m0, const ushort* __restrict__ xb,
                                         const float* __restrict__ pyP,
                                         const float* __restrict__ pxP,
                                         const float* __restrict__ mP,
                                         const ushort* __restrict__ wdts,
                                         f32x4 (&acc)[2][4]) {
  // Per-lane staged offsets: lanes 0..31 hold pixel m0+l of the tap.
  float pvy = 0.f, pvx = 0.f, pvm = 0.f;
  auto lofs = [&](int tt) {
    int t = base + tt;                   // always a real tap (exact split)
    if (l < 32) {
      size_t o = (size_t)t * NPIX + m0 + l;
      pvy = pyP[o];
      pvx = pxP[o];
      pvm = mP[o];
    }
  };
  lofs(0);
#pragma unroll
  for (int tt = 0; tt < CNT; ++tt) {
    // distribute staged offsets: group A = pixels m0+lm, B = m0+16+lm
    float pyA = __shfl(pvy, lm), pyB = __shfl(pvy, lm + 16);
    float pxA = __shfl(pvx, lm), pxB = __shfl(pvx, lm + 16);
    float mA = __shfl(pvm, lm), mB = __shfl(pvm, lm + 16);
    int ts = base + tt;
    if (tt + 1 < CNT) lofs(tt + 1);      // prefetch next tap's offsets

    uint4 UA[8], UB[8];
    f32x2 CA[4], CB[4];
    dcn_sample(pyA, pxA, mA, xb, lk, UA, CA);
    dcn_sample(pyB, pxB, mB, xb, lk, UB, CB);
    short8 aaA, abA, aaB, abB;
    dcn_pack2(UA, CA, aaA, abA);
    dcn_pack2(UB, CB, aaB, abB);

    const ushort* fb0 = wdts + (size_t)((ts * 2 + 0) * 4) * 512 + l * 8;
    const ushort* fb1 = wdts + (size_t)((ts * 2 + 1) * 4) * 512 + l * 8;
#pragma unroll
    for (int j = 0; j < 4; ++j) {
      short8 bf = *(const short8*)(fb0 + j * 512);
      acc[0][j] = __builtin_amdgcn_mfma_f32_16x16x32_bf16(aaA, bf, acc[0][j], 0, 0, 0);
      acc[1][j] = __builtin_amdgcn_mfma_f32_16x16x32_bf16(aaB, bf, acc[1][j], 0, 0, 0);
    }
#pragma unroll
    for (int j = 0; j < 4; ++j) {
      short8 bf = *(const short8*)(fb1 + j * 512);
      acc[0][j] = __builtin_amdgcn_mfma_f32_16x16x32_bf16(abA, bf, acc[0][j], 0, 0, 0);
      acc[1][j] = __builtin_amdgcn_mfma_f32_16x16x32_bf16(abB, bf, acc[1][j], 0, 0, 0);
    }
  }
}

template <int K>
__device__ __forceinline__ void dcn_body(int blk, const ushort* __restrict__ xhb,
                                         const float* __restrict__ convout,
                                         const ushort* __restrict__ wdts,
                                         float* __restrict__ out, int br_off,
                                         float* smem) {
  constexpr int KK = K * K;
  int tid = threadIdx.x, w = tid >> 6, l = tid & 63;
  int lm = l & 15, lk = l >> 4;
  int m0 = blk * 32;                       // 32 | HW
  int b = m0 / HW;
  const ushort* xb = xhb + (size_t)b * HW * C;
  const float* pyP = convout;
  const float* pxP = convout + (size_t)KK * NPIX;
  const float* mP = convout + (size_t)2 * KK * NPIX;

  f32x4 acc[2][4];
#pragma unroll
  for (int g = 0; g < 2; ++g)
#pragma unroll
    for (int j = 0; j < 4; ++j) acc[g][j] = f32x4{0.f, 0.f, 0.f, 0.f};

  // Exact per-wave tap ranges (compile-time counts keep full unrolling):
  if constexpr (K == 7) {                // 49 = 13+12+12+12
    if (w == 0) dcn_taps<7, 13>(0, l, lm, lk, m0, xb, pyP, pxP, mP, wdts, acc);
    else if (w == 1) dcn_taps<7, 12>(13, l, lm, lk, m0, xb, pyP, pxP, mP, wdts, acc);
    else if (w == 2) dcn_taps<7, 12>(25, l, lm, lk, m0, xb, pyP, pxP, mP, wdts, acc);
    else dcn_taps<7, 12>(37, l, lm, lk, m0, xb, pyP, pxP, mP, wdts, acc);
  } else if constexpr (K == 5) {         // 25 = 7+6+6+6
    if (w == 0) dcn_taps<5, 7>(0, l, lm, lk, m0, xb, pyP, pxP, mP, wdts, acc);
    else if (w == 1) dcn_taps<5, 6>(7, l, lm, lk, m0, xb, pyP, pxP, mP, wdts, acc);
    else if (w == 2) dcn_taps<5, 6>(13, l, lm, lk, m0, xb, pyP, pxP, mP, wdts, acc);
    else dcn_taps<5, 6>(19, l, lm, lk, m0, xb, pyP, pxP, mP, wdts, acc);
  } else {                               // 9 = 3+2+2+2
    if (w == 0) dcn_taps<3, 3>(0, l, lm, lk, m0, xb, pyP, pxP, mP, wdts, acc);
    else if (w == 1) dcn_taps<3, 2>(3, l, lm, lk, m0, xb, pyP, pxP, mP, wdts, acc);
    else if (w == 2) dcn_taps<3, 2>(5, l, lm, lk, m0, xb, pyP, pxP, mP, wdts, acc);
    else dcn_taps<3, 2>(7, l, lm, lk, m0, xb, pyP, pxP, mP, wdts, acc);
  }

  // K-split reduction across the 4 waves. D map: col=lm(co), row=lk*4+r(pixel).
  float (*s_red)[32][65] = (float (*)[32][65])smem;
#pragma unroll
  for (int g = 0; g < 2; ++g)
#pragma unroll
    for (int j = 0; j < 4; ++j)
#pragma unroll
      for (int r = 0; r < 4; ++r)
        s_red[w][g * 16 + lk * 4 + r][j * 16 + lm] = acc[g][j][r];
  __syncthreads();
  int rem0 = m0 - b * HW;
#pragma unroll
  for (int i = 0; i < 8; ++i) {
    int idx = i * 256 + tid;               // 8192 = 32 pix x 64 co
    int mrow = idx & 31, co = idx >> 5;
    float v = s_red[0][mrow][co] + s_red[1][mrow][co] +
              s_red[2][mrow][co] + s_red[3][mrow][co];
    out[(size_t)(b * (3 * COUT) + br_off + co) * HW + rem0 + mrow] = v;
  }
}

__global__ __launch_bounds__(256, 4) void dcn_all(
    const ushort* __restrict__ xhb,
    const float* __restrict__ co7, const ushort* __restrict__ wdts7,
    const float* __restrict__ co5, const ushort* __restrict__ wdts5,
    const float* __restrict__ co3, const ushort* __restrict__ wdts3,
    float* __restrict__ out) {
  __shared__ float smem[4 * 32 * 65];   // s_red (33.3KB; 4 blocks = 133KB/CU)
  int blk = blockIdx.x;
  if (blk < 400) dcn_body<7>(blk, xhb, co7, wdts7, out, 128, smem);
  else if (blk < 800) dcn_body<5>(blk - 400, xhb, co5, wdts5, out, 64, smem);
  else dcn_body<3>(blk - 800, xhb, co3, wdts3, out, 0, smem);
}

// ---------------------------------------------------------------------------
// Launch
// ---------------------------------------------------------------------------
extern "C" void kernel_launch(void* const* d_in, const int* in_sizes, int n_in,
                              void* d_out, int out_size, void* d_ws,
                              size_t ws_size, hipStream_t stream) {
  const float* x = (const float*)d_in[0];
  const float* w_off3 = (const float*)d_in[1];
  const float* b_off3 = (const float*)d_in[2];
  const float* w_mask3 = (const float*)d_in[3];
  const float* b_mask3 = (const float*)d_in[4];
  const float* w_dcn3 = (const float*)d_in[5];
  const float* w_off5 = (const float*)d_in[6];
  const float* b_off5 = (const float*)d_in[7];
  const float* w_mask5 = (const float*)d_in[8];
  const float* b_mask5 = (const float*)d_in[9];
  const float* w_dcn5 = (const float*)d_in[10];
  const float* w_off7 = (const float*)d_in[11];
  const float* b_off7 = (const float*)d_in[12];
  const float* w_mask7 = (const float*)d_in[13];
  const float* b_mask7 = (const float*)d_in[14];
  const float* w_dcn7 = (const float*)d_in[15];
  float* out = (float*)d_out;
  float* ws = (float*)d_ws;

  // Workspace layout (float units, 16B aligned)
  size_t off = 0;
  auto alloc = [&](size_t n) {
    size_t p = off;
    off += (n + 3) & ~(size_t)3;
    return ws + p;
  };
  ushort* xhb = (ushort*)alloc((size_t)B * HW * C / 2 + 320);  // +zero region
  float* co3 = alloc((size_t)B * HW * 27);
  float* co5 = alloc((size_t)B * HW * 75);
  float* co7 = alloc((size_t)B * HW * 147);
  ushort* wtbs3 = (ushort*)alloc(9 * 2 * 2 * 512 / 2);
  ushort* wtbs5 = (ushort*)alloc(25 * 2 * 5 * 512 / 2);
  ushort* wtbs7 = (ushort*)alloc(49 * 2 * 10 * 512 / 2);
  float* bc3 = alloc(27);
  float* bc5 = alloc(75);
  float* bc7 = alloc(147);
  ushort* wdts3 = (ushort*)alloc(9 * 2 * 4 * 512 / 2);
  ushort* wdts5 = (ushort*)alloc(25 * 2 * 4 * 512 / 2);
  ushort* wdts7 = (ushort*)alloc(49 * 2 * 4 * 512 / 2);

  // 1) transpose + all weight prep (one launch)
  setup_all<<<456, 256, 0, stream>>>(
      x, xhb,
      w_off3, b_off3, w_mask3, b_mask3, w_dcn3, wtbs3, bc3, wdts3,
      w_off5, b_off5, w_mask5, b_mask5, w_dcn5, wtbs5, bc5, wdts5,
      w_off7, b_off7, w_mask7, b_mask7, w_dcn7, wtbs7, bc7, wdts7);

  // 2) all offset+mask convs (batch-pair windows; 400 blocks per branch)
  conv_all<<<1200, 256, 0, stream>>>(xhb, wtbs7, bc7, co7, wtbs5, bc5, co5,
                                     wtbs3, bc3, co3);

  // 3) all fused deformable sampling + einsum (exact tap-split, M=32/wave)
  dcn_all<<<1200, 256, 0, stream>>>(xhb, co7, wdts7, co5, wdts5, co3, wdts3,
                                    out);
}